// Round 18
// baseline (94.766 us; speedup 1.0000x reference)
//
#include <hip/hip_runtime.h>

#define DD 128

typedef _Float16 h8 __attribute__((ext_vector_type(8)));
typedef float f4 __attribute__((ext_vector_type(4)));

// prep: W (fp32) -> Wh (fp16), zero degree counters.
__global__ __launch_bounds__(256) void prep(const float* __restrict__ W,
    _Float16* __restrict__ Wh, int* __restrict__ cnt, int N) {
  const int gid = blockIdx.x * blockDim.x + threadIdx.x;
  const int stride = gridDim.x * blockDim.x;
  for (int i = gid; i < DD * DD; i += stride) Wh[i] = (_Float16)W[i];
  for (int i = gid; i < N; i += stride) cnt[i] = 0;
}

// h16 = fp16(x @ W.T + b). Block = 64 rows; x staged via global_load_lds
// (source-swizzled); W fragments from global Wh (L2-hot) once per block.
// Prologue: slot-recording in-degree count (atomic-free CSR scatter later).
__global__ __launch_bounds__(256, 4) void gemm_mfma(const float* __restrict__ x,
    const _Float16* __restrict__ Wh, const float* __restrict__ bias,
    _Float16* __restrict__ h16, const int* __restrict__ dst,
    int* __restrict__ cnt, int* __restrict__ slot, int E, int N) {
  __shared__ __align__(16) char lds[32768 + 4096];   // xs (64x512B) | cs
  const int tid = threadIdx.x;
  const int lane = tid & 63;
  const int w    = tid >> 6;          // wave id -> cols w*32..+32
  const int lrow = lane & 15;
  const int srow = (lane >> 4) << 2;
  const int row0 = blockIdx.x * 64;

  // issue x staging: 64 rows x 512B; LDS linear, source 16B-group swizzled
#pragma unroll
  for (int i = 0; i < 8; ++i) {
    const int ol = i * 4096 + tid * 16;
    const int r  = ol >> 9;               // staged row 0..63
    const int cg = (ol >> 4) & 31;        // 16B col-group
    int grow = row0 + r; if (grow >= N) grow = N - 1;
    const char* s = (const char*)x + (size_t)grow * 512 + ((cg ^ (r & 7)) << 4);
    __builtin_amdgcn_global_load_lds(
        (const __attribute__((address_space(1))) void*)s,
        (__attribute__((address_space(3))) void*)(lds + i * 4096 + ((tid >> 6) << 10)),
        16, 0, 0);
  }

  // W fragments + bias from global Wh, once per block
  h8 wb[2][4];
  float bj[2];
#pragma unroll
  for (int jt = 0; jt < 2; ++jt) {
    const int col = w * 32 + jt * 16 + lrow;
    bj[jt] = bias[col];
#pragma unroll
    for (int ks = 0; ks < 4; ++ks)
      wb[jt][ks] = *(const h8*)(Wh + col * DD + ks * 32 + (lane >> 4) * 8);
  }

  // in-degree counting pass (overlaps staging waits — R15/R16 A/B: fusion wins)
  const int gid = blockIdx.x * 256 + tid;
  const int gsz = gridDim.x * 256;
  for (int e = gid; e < E; e += gsz) slot[e] = atomicAdd(cnt + dst[e], 1);

  __syncthreads();

  _Float16* cs = (_Float16*)(lds + 32768);
#pragma unroll
  for (int rt = 0; rt < 4; ++rt) {
    const int rowbase = row0 + rt * 16;
    if (rowbase >= N) break;             // block-uniform (tail block only)
    f4 acc[2] = {(f4){0.f,0.f,0.f,0.f}, (f4){0.f,0.f,0.f,0.f}};
#pragma unroll
    for (int ks = 0; ks < 4; ++ks) {
      const int r   = rt * 16 + lrow;
      const int cg0 = ks * 8 + (lane >> 4) * 2;
      const f4 a0 = *(const f4*)(lds + r * 512 + ((cg0 ^ (r & 7)) << 4));
      const f4 a1 = *(const f4*)(lds + r * 512 + (((cg0 + 1) ^ (r & 7)) << 4));
      h8 af;
      af[0]=(_Float16)a0.x; af[1]=(_Float16)a0.y; af[2]=(_Float16)a0.z; af[3]=(_Float16)a0.w;
      af[4]=(_Float16)a1.x; af[5]=(_Float16)a1.y; af[6]=(_Float16)a1.z; af[7]=(_Float16)a1.w;
      acc[0] = __builtin_amdgcn_mfma_f32_16x16x32_f16(af, wb[0][ks], acc[0], 0, 0, 0);
      acc[1] = __builtin_amdgcn_mfma_f32_16x16x32_f16(af, wb[1][ks], acc[1], 0, 0, 0);
    }
#pragma unroll
    for (int jt = 0; jt < 2; ++jt)
#pragma unroll
      for (int r = 0; r < 4; ++r)
        cs[(srow + r) * DD + w * 32 + jt * 16 + lrow] = (_Float16)(acc[jt][r] + bj[jt]);
    __syncthreads();
    const int frow = rowbase + (tid >> 4);
    if (frow < N) {
      const f4 v = *(const f4*)((char*)cs + tid * 16);
      *(f4*)((char*)h16 + (size_t)frow * 256 + (tid & 15) * 16) = v;
    }
    __syncthreads();
  }
}

// scan1: per-1024-chunk local exclusive scan of cnt -> rowptr, block sums ->
// bsum, dis = rsqrt(deg).
__global__ __launch_bounds__(256) void scan1(const int* __restrict__ cnt,
    int* __restrict__ rowptr, int* __restrict__ bsum, float* __restrict__ dis, int N) {
  __shared__ int s[256];
  const int tid = threadIdx.x;
  const int idx = blockIdx.x * 1024 + tid * 4;
  int4 v = {0, 0, 0, 0};
  if (idx + 3 < N) v = *(const int4*)(cnt + idx);
  else {
    if (idx + 0 < N) v.x = cnt[idx];
    if (idx + 1 < N) v.y = cnt[idx + 1];
    if (idx + 2 < N) v.z = cnt[idx + 2];
  }
  if (idx + 0 < N) dis[idx + 0] = rsqrtf((float)(v.x + 1));
  if (idx + 1 < N) dis[idx + 1] = rsqrtf((float)(v.y + 1));
  if (idx + 2 < N) dis[idx + 2] = rsqrtf((float)(v.z + 1));
  if (idx + 3 < N) dis[idx + 3] = rsqrtf((float)(v.w + 1));
  const int mysum = v.x + v.y + v.z + v.w;
  s[tid] = mysum;
  __syncthreads();
  for (int off = 1; off < 256; off <<= 1) {
    int t = (tid >= off) ? s[tid - off] : 0;
    __syncthreads();
    s[tid] += t;
    __syncthreads();
  }
  if (tid == 255) bsum[blockIdx.x] = s[255];
  int p = s[tid] - mysum;
  if (idx + 0 < N) rowptr[idx + 0] = p; p += v.x;
  if (idx + 1 < N) rowptr[idx + 1] = p; p += v.y;
  if (idx + 2 < N) rowptr[idx + 2] = p; p += v.z;
  if (idx + 3 < N) rowptr[idx + 3] = p;
}

// wave-0 exclusive scan of bsum[0..nb) into LDS (nb <= 64)
__device__ __forceinline__ void boff_scan(const int* __restrict__ bsum,
    int* __restrict__ sbof, int tid, int nb) {
  if (tid < 64) {
    const int v = (tid < nb) ? bsum[tid] : 0;
    int incl = v;
#pragma unroll
    for (int off = 1; off < 64; off <<= 1) {
      const int t = __shfl_up(incl, off);
      if (tid >= off) incl += t;
    }
    sbof[tid] = incl - v;
  }
  __syncthreads();
}

// scatter edges into dst-grouped order — atomic-free (slot from counting pass);
// 4 edges/thread via int4; block offsets scanned inline.
__global__ __launch_bounds__(256) void fill_csr(const int* __restrict__ src,
    const int* __restrict__ dst, const int* __restrict__ rowptr,
    const int* __restrict__ bsum, const int* __restrict__ slot,
    int* __restrict__ esrc, int E, int nb) {
  __shared__ int sbof[64];
  const int tid = threadIdx.x;
  boff_scan(bsum, sbof, tid, nb);
  const int e4 = blockIdx.x * 256 + tid;
  const int e  = e4 * 4;
  if (e + 3 < E) {
    const int4 s4 = ((const int4*)src)[e4];
    const int4 d4 = ((const int4*)dst)[e4];
    const int4 l4 = ((const int4*)slot)[e4];
    esrc[rowptr[d4.x] + sbof[d4.x >> 10] + l4.x] = s4.x;
    esrc[rowptr[d4.y] + sbof[d4.y >> 10] + l4.y] = s4.y;
    esrc[rowptr[d4.z] + sbof[d4.z >> 10] + l4.z] = s4.z;
    esrc[rowptr[d4.w] + sbof[d4.w >> 10] + l4.w] = s4.w;
  } else if (e < E) {
    for (int i = e; i < E; ++i) {
      const int t = dst[i];
      esrc[rowptr[t] + sbof[t >> 10] + slot[i]] = src[i];
    }
  }
}

// per node: 16 threads each own 8 columns (16B h8 gather). Edge loop runs in
// 8-edge chunks: lane q preloads esrc[k+(q&7)] + dis (no 16-way redundant
// loads), __shfl(...,j,8) distributes -> the 8 h8 gathers in the j-loop are
// fully independent (2x the in-flight depth of the old unroll-4). Remainder
// (<8) keeps the sequential order -> per-node sum order unchanged vs R12.
__global__ __launch_bounds__(256) void csr_agg(const int* __restrict__ esrc,
    const int* __restrict__ rowptr, const int* __restrict__ bsum,
    const _Float16* __restrict__ h16, const float* __restrict__ dis,
    const float* __restrict__ root, float* __restrict__ out, int N, int E, int nb) {
  __shared__ int sbof[64];
  const int tid = threadIdx.x;
  boff_scan(bsum, sbof, tid, nb);
  int gid = blockIdx.x * 256 + tid;
  if (gid >= N * 16) return;
  const int n = gid >> 4, q = gid & 15;
  const float dt  = dis[n];
  const float inv = dt * dt;            // 1/deg
  const h8* hv8 = reinterpret_cast<const h8*>(h16);
  const h8 hv = hv8[n * 16 + q];
  const float* rt = root + q * 8;
  float acc[8], ea[8];
#pragma unroll
  for (int j = 0; j < 8; ++j) {
    acc[j] = fmaxf((float)hv[j] + rt[j], 0.0f) * inv;
    ea[j] = 0.f;
  }
  const int beg = rowptr[n] + sbof[n >> 10];
  const int end = (n == N - 1) ? E : rowptr[n + 1] + sbof[(n + 1) >> 10];
  int k = beg;
  // 8-edge shuffle-distributed chunks
  for (; k + 8 <= end; k += 8) {
    const int   el = esrc[k + (q & 7)];
    const float wl = dis[el];
#pragma unroll
    for (int j = 0; j < 8; ++j) {
      const int   s  = __shfl(el, j, 8);
      const float wj = __shfl(wl, j, 8);
      const h8 g = hv8[s * 16 + q];
#pragma unroll
      for (int t = 0; t < 8; ++t) ea[t] += fmaxf((float)g[t], 0.0f) * wj;
    }
  }
  // remainder <8, unroll-4 then scalar
  for (; k + 3 < end; k += 4) {
    const int s0 = esrc[k], s1 = esrc[k + 1], s2 = esrc[k + 2], s3 = esrc[k + 3];
    const float w0 = dis[s0], w1 = dis[s1], w2 = dis[s2], w3 = dis[s3];
    const h8 g0 = hv8[s0 * 16 + q];
    const h8 g1 = hv8[s1 * 16 + q];
    const h8 g2 = hv8[s2 * 16 + q];
    const h8 g3 = hv8[s3 * 16 + q];
#pragma unroll
    for (int j = 0; j < 8; ++j)
      ea[j] += fmaxf((float)g0[j], 0.0f) * w0 + fmaxf((float)g1[j], 0.0f) * w1
             + fmaxf((float)g2[j], 0.0f) * w2 + fmaxf((float)g3[j], 0.0f) * w3;
  }
  for (; k < end; ++k) {
    const int s0 = esrc[k];
    const float w0 = dis[s0];
    const h8 g0 = hv8[s0 * 16 + q];
#pragma unroll
    for (int j = 0; j < 8; ++j) ea[j] += fmaxf((float)g0[j], 0.0f) * w0;
  }
  f4 o0, o1;
  o0.x = acc[0] + ea[0] * dt; o0.y = acc[1] + ea[1] * dt;
  o0.z = acc[2] + ea[2] * dt; o0.w = acc[3] + ea[3] * dt;
  o1.x = acc[4] + ea[4] * dt; o1.y = acc[5] + ea[5] * dt;
  o1.z = acc[6] + ea[6] * dt; o1.w = acc[7] + ea[7] * dt;
  reinterpret_cast<f4*>(out)[n * 32 + q * 2]     = o0;
  reinterpret_cast<f4*>(out)[n * 32 + q * 2 + 1] = o1;
}

extern "C" void kernel_launch(void* const* d_in, const int* in_sizes, int n_in,
                              void* d_out, int out_size, void* d_ws, size_t ws_size,
                              hipStream_t stream) {
  const float* x    = (const float*)d_in[0];
  const int*   src  = (const int*)d_in[1];
  const int*   dst  = (const int*)d_in[2];
  const float* W    = (const float*)d_in[3];
  const float* bias = (const float*)d_in[4];
  const float* root = (const float*)d_in[5];
  float* out = (float*)d_out;
  const int N = in_sizes[0] / DD;
  const int E = in_sizes[1];

  char* ws = (char*)d_ws;
  size_t off = 0;
  _Float16* h16 = (_Float16*)(ws + off); off += (size_t)N * DD * 2;
  int*   cnt    = (int*)  (ws + off); off += (size_t)N * 4;
  float* dis    = (float*)(ws + off); off += (size_t)N * 4;
  int*   rowptr = (int*)  (ws + off); off += (size_t)(N + 2) * 4;
  int*   esrc   = (int*)  (ws + off); off += (size_t)E * 4;
  int*   slot   = (int*)  (ws + off); off += (size_t)E * 4;
  int*   bsum   = (int*)  (ws + off); off += 256 * 4;
  _Float16* Wh  = (_Float16*)(ws + off); off += (size_t)DD * DD * 2;

  const int nb  = (N + 1023) / 1024;   // 49
  const int nbt = (N + 63) / 64;       // 782 row-tiles of 64
  prep<<<128, 256, 0, stream>>>(W, Wh, cnt, N);
  gemm_mfma<<<nbt, 256, 0, stream>>>(x, Wh, bias, h16, dst, cnt, slot, E, N);
  scan1<<<nb, 256, 0, stream>>>(cnt, rowptr, bsum, dis, N);
  fill_csr<<<((E + 3) / 4 + 255) / 256, 256, 0, stream>>>(src, dst, rowptr, bsum, slot, esrc, E, nb);
  csr_agg<<<(N * 16 + 255) / 256, 256, 0, stream>>>(esrc, rowptr, bsum, h16, dis, root, out, N, E, nb);
}

// Round 19
// 86.288 us; speedup vs baseline: 1.0983x; 1.0983x over previous
//
#include <hip/hip_runtime.h>

#define DD 128

typedef _Float16 h8 __attribute__((ext_vector_type(8)));
typedef float f4 __attribute__((ext_vector_type(4)));

// prep: W (fp32) -> Wh (fp16), zero degree counters.
__global__ __launch_bounds__(256) void prep(const float* __restrict__ W,
    _Float16* __restrict__ Wh, int* __restrict__ cnt, int N) {
  const int gid = blockIdx.x * blockDim.x + threadIdx.x;
  const int stride = gridDim.x * blockDim.x;
  for (int i = gid; i < DD * DD; i += stride) Wh[i] = (_Float16)W[i];
  for (int i = gid; i < N; i += stride) cnt[i] = 0;
}

// h16 = fp16(x @ W.T + b). Block = 64 rows; Wh + x staged via global_load_lds.
// Prologue: slot-recording in-degree count (slot[e] = arrival index in dst
// bucket) so the CSR scatter needs no second atomic pass. (R12 config — best
// measured at 85.99us; all R13-R18 deviations were neutral or regressions.)
__global__ __launch_bounds__(256) void gemm_mfma(const float* __restrict__ x,
    const _Float16* __restrict__ Wh, const float* __restrict__ bias,
    _Float16* __restrict__ h16, const int* __restrict__ dst,
    int* __restrict__ cnt, int* __restrict__ slot, int E, int N) {
  __shared__ __align__(16) char lds[32768 + 32768 + 4096]; // xs | whs | cs
  const int tid = threadIdx.x;
  const int gid = blockIdx.x * 256 + tid;
  const int gsz = gridDim.x * 256;
  for (int e = gid; e < E; e += gsz) slot[e] = atomicAdd(cnt + dst[e], 1);

  const int lane = tid & 63;
  const int w    = tid >> 6;          // wave id -> cols w*32..+32
  const int lrow = lane & 15;
  const int srow = (lane >> 4) << 2;
  const int row0 = blockIdx.x * 64;

  // stage Wh: 32KB linear, fully coalesced
#pragma unroll
  for (int i = 0; i < 8; ++i) {
    const char* s = (const char*)Wh + i * 4096 + tid * 16;
    __builtin_amdgcn_global_load_lds(
        (const __attribute__((address_space(1))) void*)s,
        (__attribute__((address_space(3))) void*)(lds + 32768 + i * 4096 + ((tid >> 6) << 10)),
        16, 0, 0);
  }
  // stage x: 64 rows x 512B; LDS linear, global source 16B-group swizzled
#pragma unroll
  for (int i = 0; i < 8; ++i) {
    const int ol = i * 4096 + tid * 16;
    const int r  = ol >> 9;               // staged row 0..63
    const int cg = (ol >> 4) & 31;        // 16B col-group
    int grow = row0 + r; if (grow >= N) grow = N - 1;
    const char* s = (const char*)x + (size_t)grow * 512 + ((cg ^ (r & 7)) << 4);
    __builtin_amdgcn_global_load_lds(
        (const __attribute__((address_space(1))) void*)s,
        (__attribute__((address_space(3))) void*)(lds + i * 4096 + ((tid >> 6) << 10)),
        16, 0, 0);
  }
  __syncthreads();

  // W fragments + bias from LDS, once per block
  h8 wb[2][4];
  float bj[2];
#pragma unroll
  for (int jt = 0; jt < 2; ++jt) {
    const int col = w * 32 + jt * 16 + lrow;
    bj[jt] = bias[col];
#pragma unroll
    for (int ks = 0; ks < 4; ++ks)
      wb[jt][ks] = *(const h8*)(lds + 32768 + col * 256 + ks * 64 + (lane >> 4) * 16);
  }

  _Float16* cs = (_Float16*)(lds + 65536);
#pragma unroll
  for (int rt = 0; rt < 4; ++rt) {
    const int rowbase = row0 + rt * 16;
    if (rowbase >= N) break;             // block-uniform (tail block only)
    f4 acc[2] = {(f4){0.f,0.f,0.f,0.f}, (f4){0.f,0.f,0.f,0.f}};
#pragma unroll
    for (int ks = 0; ks < 4; ++ks) {
      const int r   = rt * 16 + lrow;
      const int cg0 = ks * 8 + (lane >> 4) * 2;
      const f4 a0 = *(const f4*)(lds + r * 512 + ((cg0 ^ (r & 7)) << 4));
      const f4 a1 = *(const f4*)(lds + r * 512 + (((cg0 + 1) ^ (r & 7)) << 4));
      h8 af;
      af[0]=(_Float16)a0.x; af[1]=(_Float16)a0.y; af[2]=(_Float16)a0.z; af[3]=(_Float16)a0.w;
      af[4]=(_Float16)a1.x; af[5]=(_Float16)a1.y; af[6]=(_Float16)a1.z; af[7]=(_Float16)a1.w;
      acc[0] = __builtin_amdgcn_mfma_f32_16x16x32_f16(af, wb[0][ks], acc[0], 0, 0, 0);
      acc[1] = __builtin_amdgcn_mfma_f32_16x16x32_f16(af, wb[1][ks], acc[1], 0, 0, 0);
    }
#pragma unroll
    for (int jt = 0; jt < 2; ++jt)
#pragma unroll
      for (int r = 0; r < 4; ++r)
        cs[(srow + r) * DD + w * 32 + jt * 16 + lrow] = (_Float16)(acc[jt][r] + bj[jt]);
    __syncthreads();
    const int frow = rowbase + (tid >> 4);
    if (frow < N) {
      const f4 v = *(const f4*)((char*)cs + tid * 16);
      *(f4*)((char*)h16 + (size_t)frow * 256 + (tid & 15) * 16) = v;
    }
    __syncthreads();
  }
}

// scan1: per-1024-chunk local exclusive scan of cnt -> rowptr, block sums -> bsum,
// dis = rsqrt(deg). Global block offsets are computed inline by consumers.
__global__ __launch_bounds__(256) void scan1(const int* __restrict__ cnt,
    int* __restrict__ rowptr, int* __restrict__ bsum, float* __restrict__ dis, int N) {
  __shared__ int s[256];
  const int tid = threadIdx.x;
  const int idx = blockIdx.x * 1024 + tid * 4;
  int4 v = {0, 0, 0, 0};
  if (idx + 3 < N) v = *(const int4*)(cnt + idx);
  else {
    if (idx + 0 < N) v.x = cnt[idx];
    if (idx + 1 < N) v.y = cnt[idx + 1];
    if (idx + 2 < N) v.z = cnt[idx + 2];
  }
  if (idx + 0 < N) dis[idx + 0] = rsqrtf((float)(v.x + 1));
  if (idx + 1 < N) dis[idx + 1] = rsqrtf((float)(v.y + 1));
  if (idx + 2 < N) dis[idx + 2] = rsqrtf((float)(v.z + 1));
  if (idx + 3 < N) dis[idx + 3] = rsqrtf((float)(v.w + 1));
  const int mysum = v.x + v.y + v.z + v.w;
  s[tid] = mysum;
  __syncthreads();
  for (int off = 1; off < 256; off <<= 1) {
    int t = (tid >= off) ? s[tid - off] : 0;
    __syncthreads();
    s[tid] += t;
    __syncthreads();
  }
  if (tid == 255) bsum[blockIdx.x] = s[255];
  int p = s[tid] - mysum;
  if (idx + 0 < N) rowptr[idx + 0] = p; p += v.x;
  if (idx + 1 < N) rowptr[idx + 1] = p; p += v.y;
  if (idx + 2 < N) rowptr[idx + 2] = p; p += v.z;
  if (idx + 3 < N) rowptr[idx + 3] = p;
}

// wave-0 exclusive scan of bsum[0..nb) into LDS (nb <= 64)
__device__ __forceinline__ void boff_scan(const int* __restrict__ bsum,
    int* __restrict__ sbof, int tid, int nb) {
  if (tid < 64) {
    const int v = (tid < nb) ? bsum[tid] : 0;
    int incl = v;
#pragma unroll
    for (int off = 1; off < 64; off <<= 1) {
      const int t = __shfl_up(incl, off);
      if (tid >= off) incl += t;
    }
    sbof[tid] = incl - v;
  }
  __syncthreads();
}

// scatter edges into dst-grouped order — atomic-free (slot from counting pass);
// 4 edges/thread via int4; block offsets scanned inline.
__global__ __launch_bounds__(256) void fill_csr(const int* __restrict__ src,
    const int* __restrict__ dst, const int* __restrict__ rowptr,
    const int* __restrict__ bsum, const int* __restrict__ slot,
    int* __restrict__ esrc, int E, int nb) {
  __shared__ int sbof[64];
  const int tid = threadIdx.x;
  boff_scan(bsum, sbof, tid, nb);
  const int e4 = blockIdx.x * 256 + tid;
  const int e  = e4 * 4;
  if (e + 3 < E) {
    const int4 s4 = ((const int4*)src)[e4];
    const int4 d4 = ((const int4*)dst)[e4];
    const int4 l4 = ((const int4*)slot)[e4];
    esrc[rowptr[d4.x] + sbof[d4.x >> 10] + l4.x] = s4.x;
    esrc[rowptr[d4.y] + sbof[d4.y >> 10] + l4.y] = s4.y;
    esrc[rowptr[d4.z] + sbof[d4.z >> 10] + l4.z] = s4.z;
    esrc[rowptr[d4.w] + sbof[d4.w >> 10] + l4.w] = s4.w;
  } else if (e < E) {
    for (int i = e; i < E; ++i) {
      const int t = dst[i];
      esrc[rowptr[t] + sbof[t >> 10] + slot[i]] = src[i];
    }
  }
}

// per node: 16 threads each own 8 columns (16B h8 gather); unroll-4 edge loop;
// block offsets scanned inline; end at n=N-1 is E.
__global__ __launch_bounds__(256) void csr_agg(const int* __restrict__ esrc,
    const int* __restrict__ rowptr, const int* __restrict__ bsum,
    const _Float16* __restrict__ h16, const float* __restrict__ dis,
    const float* __restrict__ root, float* __restrict__ out, int N, int E, int nb) {
  __shared__ int sbof[64];
  const int tid = threadIdx.x;
  boff_scan(bsum, sbof, tid, nb);
  int gid = blockIdx.x * 256 + tid;
  if (gid >= N * 16) return;
  const int n = gid >> 4, q = gid & 15;
  const float dt  = dis[n];
  const float inv = dt * dt;            // 1/deg
  const h8* hv8 = reinterpret_cast<const h8*>(h16);
  const f4 r0 = reinterpret_cast<const f4*>(root)[q * 2];
  const f4 r1 = reinterpret_cast<const f4*>(root)[q * 2 + 1];
  const h8 hv = hv8[n * 16 + q];
  float acc[8];
  acc[0] = fmaxf((float)hv[0] + r0.x, 0.0f) * inv;
  acc[1] = fmaxf((float)hv[1] + r0.y, 0.0f) * inv;
  acc[2] = fmaxf((float)hv[2] + r0.z, 0.0f) * inv;
  acc[3] = fmaxf((float)hv[3] + r0.w, 0.0f) * inv;
  acc[4] = fmaxf((float)hv[4] + r1.x, 0.0f) * inv;
  acc[5] = fmaxf((float)hv[5] + r1.y, 0.0f) * inv;
  acc[6] = fmaxf((float)hv[6] + r1.z, 0.0f) * inv;
  acc[7] = fmaxf((float)hv[7] + r1.w, 0.0f) * inv;
  float ea[8] = {0.f, 0.f, 0.f, 0.f, 0.f, 0.f, 0.f, 0.f};
  const int beg = rowptr[n] + sbof[n >> 10];
  const int end = (n == N - 1) ? E : rowptr[n + 1] + sbof[(n + 1) >> 10];
  int k = beg;
  for (; k + 3 < end; k += 4) {
    const int s0 = esrc[k], s1 = esrc[k + 1], s2 = esrc[k + 2], s3 = esrc[k + 3];
    const float w0 = dis[s0], w1 = dis[s1], w2 = dis[s2], w3 = dis[s3];
    const h8 g0 = hv8[s0 * 16 + q];
    const h8 g1 = hv8[s1 * 16 + q];
    const h8 g2 = hv8[s2 * 16 + q];
    const h8 g3 = hv8[s3 * 16 + q];
#pragma unroll
    for (int j = 0; j < 8; ++j)
      ea[j] += fmaxf((float)g0[j], 0.0f) * w0 + fmaxf((float)g1[j], 0.0f) * w1
             + fmaxf((float)g2[j], 0.0f) * w2 + fmaxf((float)g3[j], 0.0f) * w3;
  }
  for (; k < end; ++k) {
    const int s0 = esrc[k];
    const float w0 = dis[s0];
    const h8 g0 = hv8[s0 * 16 + q];
#pragma unroll
    for (int j = 0; j < 8; ++j) ea[j] += fmaxf((float)g0[j], 0.0f) * w0;
  }
  f4 o0, o1;
  o0.x = acc[0] + ea[0] * dt; o0.y = acc[1] + ea[1] * dt;
  o0.z = acc[2] + ea[2] * dt; o0.w = acc[3] + ea[3] * dt;
  o1.x = acc[4] + ea[4] * dt; o1.y = acc[5] + ea[5] * dt;
  o1.z = acc[6] + ea[6] * dt; o1.w = acc[7] + ea[7] * dt;
  reinterpret_cast<f4*>(out)[n * 32 + q * 2]     = o0;
  reinterpret_cast<f4*>(out)[n * 32 + q * 2 + 1] = o1;
}

extern "C" void kernel_launch(void* const* d_in, const int* in_sizes, int n_in,
                              void* d_out, int out_size, void* d_ws, size_t ws_size,
                              hipStream_t stream) {
  const float* x    = (const float*)d_in[0];
  const int*   src  = (const int*)d_in[1];
  const int*   dst  = (const int*)d_in[2];
  const float* W    = (const float*)d_in[3];
  const float* bias = (const float*)d_in[4];
  const float* root = (const float*)d_in[5];
  float* out = (float*)d_out;
  const int N = in_sizes[0] / DD;
  const int E = in_sizes[1];

  char* ws = (char*)d_ws;
  size_t off = 0;
  _Float16* h16 = (_Float16*)(ws + off); off += (size_t)N * DD * 2;
  int*   cnt    = (int*)  (ws + off); off += (size_t)N * 4;
  float* dis    = (float*)(ws + off); off += (size_t)N * 4;
  int*   rowptr = (int*)  (ws + off); off += (size_t)(N + 2) * 4;
  int*   esrc   = (int*)  (ws + off); off += (size_t)E * 4;
  int*   slot   = (int*)  (ws + off); off += (size_t)E * 4;
  int*   bsum   = (int*)  (ws + off); off += 256 * 4;
  _Float16* Wh  = (_Float16*)(ws + off); off += (size_t)DD * DD * 2;

  const int nb  = (N + 1023) / 1024;   // 49
  const int nbt = (N + 63) / 64;       // 782 row-tiles of 64
  prep<<<128, 256, 0, stream>>>(W, Wh, cnt, N);
  gemm_mfma<<<nbt, 256, 0, stream>>>(x, Wh, bias, h16, dst, cnt, slot, E, N);
  scan1<<<nb, 256, 0, stream>>>(cnt, rowptr, bsum, dis, N);
  fill_csr<<<((E + 3) / 4 + 255) / 256, 256, 0, stream>>>(src, dst, rowptr, bsum, slot, esrc, E, nb);
  csr_agg<<<(N * 16 + 255) / 256, 256, 0, stream>>>(esrc, rowptr, bsum, h16, dis, root, out, N, E, nb);
}